// Round 10
// baseline (199.036 us; speedup 1.0000x reference)
//
#include <hip/hip_runtime.h>

// Round-10: R9's idea (84 vs 108 LDS instrs/row) with R5's register
// discipline.  R9 spilled because it held 7 float4s of table live at once
// under the 64-VGPR cap of a 1024-thread block.  Fix: per (s,t0) read kv
// (the 3 k8 tails) once, then load + IMMEDIATELY consume each tile's two
// float4s, reusing the same two registers for all three tiles -> live table
// floats <= 12, working set ~45 < 64.
// Everything else byte-identical to R5 (best clean run, 73.9us):
// 256 blocks x 1024 threads (1 build/CU), 1 row/thread, x loaded at entry,
// bias folded into tabs[0][0][0].
// Packed layout tabs[4][3][28]: [0..7]=tile t1=0, [8..15]=t1=1,
// [16..23]=t1=2, [24..26]=k8 tails of t1=0,1,2.

__device__ __forceinline__ float layer_angle(const float* __restrict__ w,
                                             int l, int idx) {
    float ang = 0.f;
    #pragma unroll
    for (int g = 0; g < 4; ++g) {
        int cb = (idx >> (3 - g)) & 1;                 // control = wire g
        int tb = (idx >> (3 - ((g + 1) & 3))) & 1;     // target  = wire (g+1)%4
        if (cb) ang += (tb ? 0.5f : -0.5f) * w[l * 4 + g];
    }
    return ang;
}

__global__ __launch_bounds__(1024) void fused_qcircuit(
    const float* __restrict__ x,
    const float* __restrict__ weights,
    const float* __restrict__ lin_w,
    const float* __restrict__ lin_b,
    float* __restrict__ out,
    int nrows)
{
    __shared__ float2 U1[256], U2[256], U[256];   // row-major [i*16+j]
    __shared__ float zeta[4][16];
    __shared__ float G[4][256];
    __shared__ float A[4][3][64];
    __shared__ float B[4][9][16];
    __shared__ float C1[4][27][4];
    __shared__ __align__(16) float tabs[4][3][28];  // packed tile-triples

    int t = threadIdx.x;            // 0..1023
    int i = t >> 4, j = t & 15;     // build-phase coords (t<256 only)

    // ---- x load at entry: 16 VGPR, latency hidden under the build ----
    int b = blockIdx.x * blockDim.x + t;
    int bc = b < nrows ? b : 0;
    const float4* xp = (const float4*)(x + (size_t)bc * 16);
    float4 xa = xp[0], xb = xp[1], xc = xp[2], xd = xp[3];

    // ---- table build: matmuls on t<256, folds on all 1024 ----
    if (t < 256) {
        // U1 = Hhat * D0   (Hhat[i][j] = (-1)^popc(i&j), unnormalized)
        float sgn = (__popc(i & j) & 1) ? -1.f : 1.f;
        float a = layer_angle(weights, 0, j);
        U1[t] = make_float2(sgn * __cosf(a), sgn * __sinf(a));
    }
    // zeta[s][k] = sum_w (lin_w[0,4s+w]-lin_w[1,4s+w]) * (-1)^{bit(3-w) of k}
    if (t < 64) {
        int s = t >> 4, k = t & 15;
        float z = 0.f;
        #pragma unroll
        for (int w = 0; w < 4; ++w) {
            float sg = ((k >> (3 - w)) & 1) ? -1.f : 1.f;
            z += (lin_w[s * 4 + w] - lin_w[16 + s * 4 + w]) * sg;
        }
        zeta[s][k] = z;
    }
    __syncthreads();
    // U2 = Hhat * D1 * U1
    if (t < 256) {
        float ar = 0.f, ai = 0.f;
        for (int k = 0; k < 16; ++k) {
            float sgn = (__popc(i & k) & 1) ? -1.f : 1.f;
            float a = layer_angle(weights, 1, k);
            float cr = sgn * __cosf(a), ci = sgn * __sinf(a);
            float2 u = U1[k * 16 + j];
            ar += cr * u.x - ci * u.y;
            ai += cr * u.y + ci * u.x;
        }
        U2[t] = make_float2(ar, ai);
    }
    __syncthreads();
    // U = Hhat * D2 * U2
    if (t < 256) {
        float ar = 0.f, ai = 0.f;
        for (int k = 0; k < 16; ++k) {
            float sgn = (__popc(i & k) & 1) ? -1.f : 1.f;
            float a = layer_angle(weights, 2, k);
            float cr = sgn * __cosf(a), ci = sgn * __sinf(a);
            float2 u = U2[k * 16 + j];
            ar += cr * u.x - ci * u.y;
            ai += cr * u.y + ci * u.x;
        }
        U[t] = make_float2(ar, ai);
    }
    __syncthreads();
    // G[s][i*16+j] = sum_k zeta[s][k] * Re(conj(U[k,i]) U[k,j])
    if (t < 256) {
        float g[4] = {0, 0, 0, 0};
        for (int k = 0; k < 16; ++k) {
            float2 uki = U[k * 16 + i], ukj = U[k * 16 + j];
            float p = uki.x * ukj.x + uki.y * ukj.y;
            #pragma unroll
            for (int s = 0; s < 4; ++s) g[s] += zeta[s][k] * p;
        }
        #pragma unroll
        for (int s = 0; s < 4; ++s) G[s][t] = g[s];
    }
    __syncthreads();
    // Fold wire3 (LSB): A[s][t3][ih*8+jh]
    for (int e = t; e < 768; e += 1024) {
        int m = e / 192, r = e % 192;
        int t3 = r / 64, q = r % 64;
        int ih = q >> 3, jh = q & 7;
        float g00 = G[m][(ih * 2 + 0) * 16 + jh * 2 + 0];
        float g01 = G[m][(ih * 2 + 0) * 16 + jh * 2 + 1];
        float g10 = G[m][(ih * 2 + 1) * 16 + jh * 2 + 0];
        float g11 = G[m][(ih * 2 + 1) * 16 + jh * 2 + 1];
        A[m][t3][q] = (t3 == 0) ? g00 + g11 : (t3 == 1) ? g00 - g11 : g01 + g10;
    }
    __syncthreads();
    // Fold wire2: B[s][t2*3+t3][ih*4+jh]
    for (int e = t; e < 576; e += 1024) {
        int m = e / 144, r = e % 144;
        int t2 = r / 48; r %= 48;
        int t3 = r / 16, q = r % 16;
        int ih = q >> 2, jh = q & 3;
        float a00 = A[m][t3][(ih * 2 + 0) * 8 + jh * 2 + 0];
        float a01 = A[m][t3][(ih * 2 + 0) * 8 + jh * 2 + 1];
        float a10 = A[m][t3][(ih * 2 + 1) * 8 + jh * 2 + 0];
        float a11 = A[m][t3][(ih * 2 + 1) * 8 + jh * 2 + 1];
        B[m][t2 * 3 + t3][q] = (t2 == 0) ? a00 + a11
                             : (t2 == 1) ? a00 - a11 : a01 + a10;
    }
    __syncthreads();
    // Fold wire1: C1[s][t1*9+t2*3+t3][ih*2+jh]
    for (int e = t; e < 432; e += 1024) {
        int m = e / 108, r = e % 108;
        int t1 = r / 36; r %= 36;
        int t23 = r / 4, q = r % 4;
        int ih = q >> 1, jh = q & 1;
        float b00 = B[m][t23][(ih * 2 + 0) * 4 + jh * 2 + 0];
        float b01 = B[m][t23][(ih * 2 + 0) * 4 + jh * 2 + 1];
        float b10 = B[m][t23][(ih * 2 + 1) * 4 + jh * 2 + 0];
        float b11 = B[m][t23][(ih * 2 + 1) * 4 + jh * 2 + 1];
        C1[m][t1 * 9 + t23][q] = (t1 == 0) ? b00 + b11
                               : (t1 == 1) ? b00 - b11 : b01 + b10;
    }
    __syncthreads();
    // Fold wire0 + write PACKED tiles.  Scale: (1/64)^2 H-norm, (1/2)^4
    // half-angle basis.  lin_b difference folded into tabs[0][0][0].
    {
        const float scale = 1.f / 65536.f;
        float bias = lin_b[0] - lin_b[1];
        for (int e = t; e < 324; e += 1024) {
            int m = e / 81, r = e % 81;
            int t0 = r / 27, t123 = r % 27;
            const float* c = C1[m][t123];
            float v = (t0 == 0) ? c[0] + c[3] : (t0 == 1) ? c[0] - c[3]
                                              : c[1] + c[2];
            float val = v * scale;
            if (e == 0) val += bias;
            int t1 = t123 / 9, k = t123 % 9;
            if (k < 8) tabs[m][t0][t1 * 8 + k] = val;
            else       tabs[m][t0][24 + t1]   = val;
        }
    }
    __syncthreads();

    // ---- batch compute: 1 row/thread, 7x b128 per (s,t0), low pressure ----
    float xs[16] = {xa.x, xa.y, xa.z, xa.w, xb.x, xb.y, xb.z, xb.w,
                    xc.x, xc.y, xc.z, xc.w, xd.x, xd.y, xd.z, xd.w};
    float d = 0.f;
    #pragma unroll
    for (int s = 0; s < 4; ++s) {
        const int b0 = ((s >> 1) << 3) + ((s & 1) << 1);
        // wires 0,1,2,3 of circuit s -> x indices b0, b0+1, b0+4, b0+5
        float C0, S0, C1v, S1, C2, S2, C3, S3;
        __sincosf(xs[b0],     &S0,  &C0);
        __sincosf(xs[b0 + 1], &S1,  &C1v);
        __sincosf(xs[b0 + 4], &S2,  &C2);
        __sincosf(xs[b0 + 5], &S3,  &C3);
        #pragma unroll
        for (int t0 = 0; t0 < 3; ++t0) {
            const float4* g = (const float4*)&tabs[s][t0][0];
            float4 kv = g[6];                 // k8 tails of t1=0,1,2
            float acc;
            float4 pa, pb;                    // reused for all three tiles
            {   // t1 = 0
                pa = g[0]; pb = g[1];
                float u0 = fmaf(S3, pa.z, fmaf(C3, pa.y, pa.x));
                float u1 = fmaf(S3, pb.y, fmaf(C3, pb.x, pa.w));
                float u2 = fmaf(S3, kv.x, fmaf(C3, pb.w, pb.z));
                acc = fmaf(S2, u2, fmaf(C2, u1, u0));
            }
            {   // t1 = 1
                pa = g[2]; pb = g[3];
                float u0 = fmaf(S3, pa.z, fmaf(C3, pa.y, pa.x));
                float u1 = fmaf(S3, pb.y, fmaf(C3, pb.x, pa.w));
                float u2 = fmaf(S3, kv.y, fmaf(C3, pb.w, pb.z));
                float a1 = fmaf(S2, u2, fmaf(C2, u1, u0));
                acc = fmaf(C1v, a1, acc);
            }
            {   // t1 = 2
                pa = g[4]; pb = g[5];
                float u0 = fmaf(S3, pa.z, fmaf(C3, pa.y, pa.x));
                float u1 = fmaf(S3, pb.y, fmaf(C3, pb.x, pa.w));
                float u2 = fmaf(S3, kv.z, fmaf(C3, pb.w, pb.z));
                float a1 = fmaf(S2, u2, fmaf(C2, u1, u0));
                acc = fmaf(S1, a1, acc);
            }
            d = (t0 == 0) ? d + acc
              : (t0 == 1) ? fmaf(C0, acc, d)
                          : fmaf(S0, acc, d);
        }
    }

    if (b < nrows) {
        // bias already folded into tabs[0][0][0]; softmax over 2 = sigmoid
        float p0 = 1.f / (1.f + __expf(-d));
        *(float2*)(out + (size_t)b * 2) = make_float2(p0, 1.f - p0);
    }

    // grid-stride fallback (dead when grid covers nrows exactly)
    for (int row = b + gridDim.x * blockDim.x; row < nrows;
         row += gridDim.x * blockDim.x) {
        const float4* xq = (const float4*)(x + (size_t)row * 16);
        float4 ya = xq[0], yb = xq[1], yc = xq[2], yd = xq[3];
        float ys[16] = {ya.x, ya.y, ya.z, ya.w, yb.x, yb.y, yb.z, yb.w,
                        yc.x, yc.y, yc.z, yc.w, yd.x, yd.y, yd.z, yd.w};
        float dd = 0.f;
        #pragma unroll
        for (int s = 0; s < 4; ++s) {
            const int b0 = ((s >> 1) << 3) + ((s & 1) << 1);
            float C0, S0, C1v, S1, C2, S2, C3, S3;
            __sincosf(ys[b0],     &S0,  &C0);
            __sincosf(ys[b0 + 1], &S1,  &C1v);
            __sincosf(ys[b0 + 4], &S2,  &C2);
            __sincosf(ys[b0 + 5], &S3,  &C3);
            #pragma unroll
            for (int t0 = 0; t0 < 3; ++t0) {
                const float4* g = (const float4*)&tabs[s][t0][0];
                float4 kv = g[6];
                float acc;
                float4 pa, pb;
                {
                    pa = g[0]; pb = g[1];
                    float u0 = fmaf(S3, pa.z, fmaf(C3, pa.y, pa.x));
                    float u1 = fmaf(S3, pb.y, fmaf(C3, pb.x, pa.w));
                    float u2 = fmaf(S3, kv.x, fmaf(C3, pb.w, pb.z));
                    acc = fmaf(S2, u2, fmaf(C2, u1, u0));
                }
                {
                    pa = g[2]; pb = g[3];
                    float u0 = fmaf(S3, pa.z, fmaf(C3, pa.y, pa.x));
                    float u1 = fmaf(S3, pb.y, fmaf(C3, pb.x, pa.w));
                    float u2 = fmaf(S3, kv.y, fmaf(C3, pb.w, pb.z));
                    float a1 = fmaf(S2, u2, fmaf(C2, u1, u0));
                    acc = fmaf(C1v, a1, acc);
                }
                {
                    pa = g[4]; pb = g[5];
                    float u0 = fmaf(S3, pa.z, fmaf(C3, pa.y, pa.x));
                    float u1 = fmaf(S3, pb.y, fmaf(C3, pb.x, pa.w));
                    float u2 = fmaf(S3, kv.z, fmaf(C3, pb.w, pb.z));
                    float a1 = fmaf(S2, u2, fmaf(C2, u1, u0));
                    acc = fmaf(S1, a1, acc);
                }
                dd = (t0 == 0) ? dd + acc
                   : (t0 == 1) ? fmaf(C0, acc, dd)
                               : fmaf(S0, acc, dd);
            }
        }
        float p0 = 1.f / (1.f + __expf(-dd));
        *(float2*)(out + (size_t)row * 2) = make_float2(p0, 1.f - p0);
    }
}

extern "C" void kernel_launch(void* const* d_in, const int* in_sizes, int n_in,
                              void* d_out, int out_size, void* d_ws, size_t ws_size,
                              hipStream_t stream) {
    const float* x       = (const float*)d_in[0];
    const float* weights = (const float*)d_in[1];
    const float* lin_w   = (const float*)d_in[2];
    const float* lin_b   = (const float*)d_in[3];
    float* out = (float*)d_out;

    int nrows = in_sizes[0] / 16;
    int block = 1024;
    int grid = (nrows + block - 1) / block;
    if (grid < 1) grid = 1;
    fused_qcircuit<<<grid, block, 0, stream>>>(x, weights, lin_w, lin_b, out, nrows);
}

// Round 12
// 73.703 us; speedup vs baseline: 2.7005x; 2.7005x over previous
//
#include <hip/hip_runtime.h>

// Round-12: resubmit of Round-5/Round-11 kernel (best clean measurement,
// 73.9us).  Round-11's bench failed on infrastructure (container failed
// twice), not on the kernel — this source is byte-equivalent to Round-5's
// verified run.
// Structure: 256 blocks x 1024 threads (1 block/CU, 4 waves/SIMD); table
// built once per CU (matmuls on t<256, folds on all 1024); 1 row/thread;
// x loaded at entry (hidden under build); bias folded into tabs[0][0][0];
// softmax(2) == sigmoid of logit difference.

__device__ __forceinline__ float layer_angle(const float* __restrict__ w,
                                             int l, int idx) {
    float ang = 0.f;
    #pragma unroll
    for (int g = 0; g < 4; ++g) {
        int cb = (idx >> (3 - g)) & 1;                 // control = wire g
        int tb = (idx >> (3 - ((g + 1) & 3))) & 1;     // target  = wire (g+1)%4
        if (cb) ang += (tb ? 0.5f : -0.5f) * w[l * 4 + g];
    }
    return ang;
}

__global__ __launch_bounds__(1024) void fused_qcircuit(
    const float* __restrict__ x,
    const float* __restrict__ weights,
    const float* __restrict__ lin_w,
    const float* __restrict__ lin_b,
    float* __restrict__ out,
    int nrows)
{
    __shared__ float2 U1[256], U2[256], U[256];   // row-major [i*16+j]
    __shared__ float zeta[4][16];
    __shared__ float G[4][256];
    __shared__ float A[4][3][64];
    __shared__ float B[4][9][16];
    __shared__ float C1[4][27][4];
    __shared__ __align__(16) float tabs[4][9][12];  // [s][t0*3+t1][k] pad 12

    int t = threadIdx.x;            // 0..1023
    int i = t >> 4, j = t & 15;     // build-phase coords (t<256 only)

    // ---- x load at entry: 16 VGPR, latency hidden under the build ----
    int b = blockIdx.x * blockDim.x + t;
    int bc = b < nrows ? b : 0;
    const float4* xp = (const float4*)(x + (size_t)bc * 16);
    float4 xa = xp[0], xb = xp[1], xc = xp[2], xd = xp[3];

    // ---- table build: matmuls on t<256, folds on all 1024 ----
    if (t < 256) {
        // U1 = Hhat * D0   (Hhat[i][j] = (-1)^popc(i&j), unnormalized)
        float sgn = (__popc(i & j) & 1) ? -1.f : 1.f;
        float a = layer_angle(weights, 0, j);
        U1[t] = make_float2(sgn * __cosf(a), sgn * __sinf(a));
    }
    // zeta[s][k] = sum_w (lin_w[0,4s+w]-lin_w[1,4s+w]) * (-1)^{bit(3-w) of k}
    if (t < 64) {
        int s = t >> 4, k = t & 15;
        float z = 0.f;
        #pragma unroll
        for (int w = 0; w < 4; ++w) {
            float sg = ((k >> (3 - w)) & 1) ? -1.f : 1.f;
            z += (lin_w[s * 4 + w] - lin_w[16 + s * 4 + w]) * sg;
        }
        zeta[s][k] = z;
    }
    __syncthreads();
    // U2 = Hhat * D1 * U1
    if (t < 256) {
        float ar = 0.f, ai = 0.f;
        for (int k = 0; k < 16; ++k) {
            float sgn = (__popc(i & k) & 1) ? -1.f : 1.f;
            float a = layer_angle(weights, 1, k);
            float cr = sgn * __cosf(a), ci = sgn * __sinf(a);
            float2 u = U1[k * 16 + j];
            ar += cr * u.x - ci * u.y;
            ai += cr * u.y + ci * u.x;
        }
        U2[t] = make_float2(ar, ai);
    }
    __syncthreads();
    // U = Hhat * D2 * U2
    if (t < 256) {
        float ar = 0.f, ai = 0.f;
        for (int k = 0; k < 16; ++k) {
            float sgn = (__popc(i & k) & 1) ? -1.f : 1.f;
            float a = layer_angle(weights, 2, k);
            float cr = sgn * __cosf(a), ci = sgn * __sinf(a);
            float2 u = U2[k * 16 + j];
            ar += cr * u.x - ci * u.y;
            ai += cr * u.y + ci * u.x;
        }
        U[t] = make_float2(ar, ai);
    }
    __syncthreads();
    // G[s][i*16+j] = sum_k zeta[s][k] * Re(conj(U[k,i]) U[k,j])
    if (t < 256) {
        float g[4] = {0, 0, 0, 0};
        for (int k = 0; k < 16; ++k) {
            float2 uki = U[k * 16 + i], ukj = U[k * 16 + j];
            float p = uki.x * ukj.x + uki.y * ukj.y;
            #pragma unroll
            for (int s = 0; s < 4; ++s) g[s] += zeta[s][k] * p;
        }
        #pragma unroll
        for (int s = 0; s < 4; ++s) G[s][t] = g[s];
    }
    __syncthreads();
    // Fold wire3 (LSB): A[s][t3][ih*8+jh]
    for (int e = t; e < 768; e += 1024) {
        int m = e / 192, r = e % 192;
        int t3 = r / 64, q = r % 64;
        int ih = q >> 3, jh = q & 7;
        float g00 = G[m][(ih * 2 + 0) * 16 + jh * 2 + 0];
        float g01 = G[m][(ih * 2 + 0) * 16 + jh * 2 + 1];
        float g10 = G[m][(ih * 2 + 1) * 16 + jh * 2 + 0];
        float g11 = G[m][(ih * 2 + 1) * 16 + jh * 2 + 1];
        A[m][t3][q] = (t3 == 0) ? g00 + g11 : (t3 == 1) ? g00 - g11 : g01 + g10;
    }
    __syncthreads();
    // Fold wire2: B[s][t2*3+t3][ih*4+jh]
    for (int e = t; e < 576; e += 1024) {
        int m = e / 144, r = e % 144;
        int t2 = r / 48; r %= 48;
        int t3 = r / 16, q = r % 16;
        int ih = q >> 2, jh = q & 3;
        float a00 = A[m][t3][(ih * 2 + 0) * 8 + jh * 2 + 0];
        float a01 = A[m][t3][(ih * 2 + 0) * 8 + jh * 2 + 1];
        float a10 = A[m][t3][(ih * 2 + 1) * 8 + jh * 2 + 0];
        float a11 = A[m][t3][(ih * 2 + 1) * 8 + jh * 2 + 1];
        B[m][t2 * 3 + t3][q] = (t2 == 0) ? a00 + a11
                             : (t2 == 1) ? a00 - a11 : a01 + a10;
    }
    __syncthreads();
    // Fold wire1: C1[s][t1*9+t2*3+t3][ih*2+jh]
    for (int e = t; e < 432; e += 1024) {
        int m = e / 108, r = e % 108;
        int t1 = r / 36; r %= 36;
        int t23 = r / 4, q = r % 4;
        int ih = q >> 1, jh = q & 1;
        float b00 = B[m][t23][(ih * 2 + 0) * 4 + jh * 2 + 0];
        float b01 = B[m][t23][(ih * 2 + 0) * 4 + jh * 2 + 1];
        float b10 = B[m][t23][(ih * 2 + 1) * 4 + jh * 2 + 0];
        float b11 = B[m][t23][(ih * 2 + 1) * 4 + jh * 2 + 1];
        C1[m][t1 * 9 + t23][q] = (t1 == 0) ? b00 + b11
                               : (t1 == 1) ? b00 - b11 : b01 + b10;
    }
    __syncthreads();
    // Fold wire0 + write padded tiles.  Scale: (1/64)^2 H-norm, (1/2)^4
    // half-angle basis.  lin_b difference folded into tabs[0][0][0].
    {
        const float scale = 1.f / 65536.f;
        float bias = lin_b[0] - lin_b[1];
        for (int e = t; e < 324; e += 1024) {
            int m = e / 81, r = e % 81;
            int t0 = r / 27, t123 = r % 27;
            const float* c = C1[m][t123];
            float v = (t0 == 0) ? c[0] + c[3] : (t0 == 1) ? c[0] - c[3]
                                              : c[1] + c[2];
            float val = v * scale;
            if (e == 0) val += bias;
            int t1 = t123 / 9, k = t123 % 9;
            tabs[m][t0 * 3 + t1][k] = val;
        }
    }
    __syncthreads();

    // ---- batch compute: R4-K2 / R5 loop (proven-clean codegen) ----
    float xs[16] = {xa.x, xa.y, xa.z, xa.w, xb.x, xb.y, xb.z, xb.w,
                    xc.x, xc.y, xc.z, xc.w, xd.x, xd.y, xd.z, xd.w};
    float d = 0.f;
    #pragma unroll
    for (int s = 0; s < 4; ++s) {
        const int b0 = ((s >> 1) << 3) + ((s & 1) << 1);
        // wires 0,1,2,3 of circuit s -> x indices b0, b0+1, b0+4, b0+5
        float C0, S0, C1v, S1, C2, S2, C3, S3;
        __sincosf(xs[b0],     &S0,  &C0);
        __sincosf(xs[b0 + 1], &S1,  &C1v);
        __sincosf(xs[b0 + 4], &S2,  &C2);
        __sincosf(xs[b0 + 5], &S3,  &C3);
        #pragma unroll
        for (int t0 = 0; t0 < 3; ++t0) {
            float acc = 0.f;
            #pragma unroll
            for (int t1 = 0; t1 < 3; ++t1) {
                const float* tp = &tabs[s][t0 * 3 + t1][0];
                float4 q0 = *(const float4*)tp;        // k0..k3
                float4 q1 = *(const float4*)(tp + 4);  // k4..k7
                float  k8 = tp[8];
                float u0 = fmaf(S3, q0.z, fmaf(C3, q0.y, q0.x));
                float u1 = fmaf(S3, q1.y, fmaf(C3, q1.x, q0.w));
                float u2 = fmaf(S3, k8,   fmaf(C3, q1.w, q1.z));
                float a1 = fmaf(S2, u2, fmaf(C2, u1, u0));
                acc = (t1 == 0) ? acc + a1
                    : (t1 == 1) ? fmaf(C1v, a1, acc)
                                : fmaf(S1,  a1, acc);
            }
            d = (t0 == 0) ? d + acc
              : (t0 == 1) ? fmaf(C0, acc, d)
                          : fmaf(S0, acc, d);
        }
    }

    if (b < nrows) {
        // bias already folded into tabs[0][0][0]; softmax over 2 = sigmoid
        float p0 = 1.f / (1.f + __expf(-d));
        *(float2*)(out + (size_t)b * 2) = make_float2(p0, 1.f - p0);
    }

    // grid-stride fallback (dead when grid covers nrows exactly)
    for (int row = b + gridDim.x * blockDim.x; row < nrows;
         row += gridDim.x * blockDim.x) {
        const float4* xq = (const float4*)(x + (size_t)row * 16);
        float4 ya = xq[0], yb = xq[1], yc = xq[2], yd = xq[3];
        float ys[16] = {ya.x, ya.y, ya.z, ya.w, yb.x, yb.y, yb.z, yb.w,
                        yc.x, yc.y, yc.z, yc.w, yd.x, yd.y, yd.z, yd.w};
        float dd = 0.f;
        #pragma unroll
        for (int s = 0; s < 4; ++s) {
            const int b0 = ((s >> 1) << 3) + ((s & 1) << 1);
            float C0, S0, C1v, S1, C2, S2, C3, S3;
            __sincosf(ys[b0],     &S0,  &C0);
            __sincosf(ys[b0 + 1], &S1,  &C1v);
            __sincosf(ys[b0 + 4], &S2,  &C2);
            __sincosf(ys[b0 + 5], &S3,  &C3);
            #pragma unroll
            for (int t0 = 0; t0 < 3; ++t0) {
                float acc = 0.f;
                #pragma unroll
                for (int t1 = 0; t1 < 3; ++t1) {
                    const float* tp = &tabs[s][t0 * 3 + t1][0];
                    float4 q0 = *(const float4*)tp;
                    float4 q1 = *(const float4*)(tp + 4);
                    float  k8 = tp[8];
                    float u0 = fmaf(S3, q0.z, fmaf(C3, q0.y, q0.x));
                    float u1 = fmaf(S3, q1.y, fmaf(C3, q1.x, q0.w));
                    float u2 = fmaf(S3, k8,   fmaf(C3, q1.w, q1.z));
                    float a1 = fmaf(S2, u2, fmaf(C2, u1, u0));
                    acc = (t1 == 0) ? acc + a1
                        : (t1 == 1) ? fmaf(C1v, a1, acc)
                                    : fmaf(S1,  a1, acc);
                }
                dd = (t0 == 0) ? dd + acc
                   : (t0 == 1) ? fmaf(C0, acc, dd)
                               : fmaf(S0, acc, dd);
            }
        }
        float p0 = 1.f / (1.f + __expf(-dd));
        *(float2*)(out + (size_t)row * 2) = make_float2(p0, 1.f - p0);
    }
}

extern "C" void kernel_launch(void* const* d_in, const int* in_sizes, int n_in,
                              void* d_out, int out_size, void* d_ws, size_t ws_size,
                              hipStream_t stream) {
    const float* x       = (const float*)d_in[0];
    const float* weights = (const float*)d_in[1];
    const float* lin_w   = (const float*)d_in[2];
    const float* lin_b   = (const float*)d_in[3];
    float* out = (float*)d_out;

    int nrows = in_sizes[0] / 16;
    int block = 1024;
    int grid = (nrows + block - 1) / block;
    if (grid < 1) grid = 1;
    fused_qcircuit<<<grid, block, 0, stream>>>(x, weights, lin_w, lin_b, out, nrows);
}